// Round 1
// baseline (1142.265 us; speedup 1.0000x reference)
//
#include <hip/hip_runtime.h>
#include <math.h>

#define N_NODES 100000
#define N_EDGES 200000
#define NNZ_    1600000
#define INC  128
#define OUTC 128
#define STAR_ 64
#define NEG 0.2f
#define MAXC 128

__device__ __forceinline__ float leaky(float x){ return x > 0.f ? x : NEG*x; }
__device__ __forceinline__ float elu1(float x){ return x > 0.f ? x : __expf(x)-1.f; }

// ---------------- GEMM1: X_init = X@Wx+bx (into d_out), X_feat = X@Wv+bv ----------------
__global__ __launch_bounds__(128) void k_gemm1(const float* __restrict__ X,
    const float* __restrict__ Wx, const float* __restrict__ bx,
    const float* __restrict__ Wv, const float* __restrict__ bv,
    float* __restrict__ Xinit, float* __restrict__ Xfeat) {
  __shared__ float xS[8][132];          // row stride 132 floats: 16B-aligned rows, conflict-free writes
  const int c = threadIdx.x;
  const int r0 = blockIdx.x * 8;
  #pragma unroll
  for (int t = 0; t < 8; ++t) xS[t][c] = X[(size_t)(r0+t)*INC + c];
  __syncthreads();
  float ai[8], af[8];
  const float bxc = bx[c], bvc = bv[c];
  #pragma unroll
  for (int t = 0; t < 8; ++t) { ai[t] = bxc; af[t] = bvc; }
  for (int k = 0; k < INC; k += 4) {
    const float wx0 = Wx[(k+0)*OUTC + c], wx1 = Wx[(k+1)*OUTC + c],
                wx2 = Wx[(k+2)*OUTC + c], wx3 = Wx[(k+3)*OUTC + c];
    const float wv0 = Wv[(k+0)*OUTC + c], wv1 = Wv[(k+1)*OUTC + c],
                wv2 = Wv[(k+2)*OUTC + c], wv3 = Wv[(k+3)*OUTC + c];
    #pragma unroll
    for (int t = 0; t < 8; ++t) {
      const float4 x4 = *(const float4*)&xS[t][k];
      ai[t] += x4.x*wx0 + x4.y*wx1 + x4.z*wx2 + x4.w*wx3;
      af[t] += x4.x*wv0 + x4.y*wv1 + x4.z*wv2 + x4.w*wv3;
    }
  }
  #pragma unroll
  for (int t = 0; t < 8; ++t) {
    Xinit[(size_t)(r0+t)*OUTC + c] = ai[t];
    Xfeat[(size_t)(r0+t)*OUTC + c] = af[t];
  }
}

// ---------------- scores = X_feat @ a_vec ----------------
__global__ __launch_bounds__(256) void k_scores(const float* __restrict__ Xfeat,
    const float* __restrict__ a, float* __restrict__ scores) {
  const int lane = threadIdx.x & 63;
  const int w = threadIdx.x >> 6;
  const int r = blockIdx.x * 4 + w;
  const float* row = Xfeat + (size_t)r * OUTC;
  float p = row[lane] * a[lane] + row[64+lane] * a[64+lane];
  #pragma unroll
  for (int o = 32; o; o >>= 1) p += __shfl_xor(p, o, 64);
  if (lane == 0) scores[r] = p;
}

// ---------------- CSR build ----------------
__global__ void k_hist(const int* __restrict__ V, const int* __restrict__ E,
                       int* cntE, int* cntV) {
  const int i = blockIdx.x*256 + threadIdx.x;
  atomicAdd(&cntE[E[i]], 1);
  atomicAdd(&cntV[V[i]], 1);
}

__global__ void k_scan_block(const int* __restrict__ in, int* __restrict__ out,
                             int* __restrict__ partials, int n) {
  __shared__ int s[256];
  const int tid = threadIdx.x;
  const int i = blockIdx.x*256 + tid;
  const int v = (i < n) ? in[i] : 0;
  s[tid] = v; __syncthreads();
  for (int o = 1; o < 256; o <<= 1) {
    const int u = (tid >= o) ? s[tid-o] : 0;
    __syncthreads();
    s[tid] += u;
    __syncthreads();
  }
  if (i < n) out[i] = s[tid] - v;            // block-local exclusive
  if (tid == 255) partials[blockIdx.x] = s[255];
}

__global__ void k_scan_partials(int* partials, int nb) {
  __shared__ int s[1024];
  const int tid = threadIdx.x;
  const int v = (tid < nb) ? partials[tid] : 0;
  s[tid] = v; __syncthreads();
  for (int o = 1; o < 1024; o <<= 1) {
    const int u = (tid >= o) ? s[tid-o] : 0;
    __syncthreads();
    s[tid] += u;
    __syncthreads();
  }
  if (tid < nb) partials[tid] = s[tid] - v;  // exclusive block offsets
}

__global__ void k_add_off(int* __restrict__ out, const int* __restrict__ partials, int n) {
  const int i = blockIdx.x*256 + threadIdx.x;
  if (i < n) out[i] += partials[blockIdx.x];
}

__global__ void k_fill(const int* __restrict__ V, const int* __restrict__ E,
    const int* __restrict__ startsE, int* fillE, int* __restrict__ idxE,
    const int* __restrict__ startsV, int* fillV, int* __restrict__ idxV) {
  const int i = blockIdx.x*256 + threadIdx.x;
  const int e = E[i]; idxE[startsE[e] + atomicAdd(&fillE[e],1)] = i;
  const int v = V[i]; idxV[startsV[v] + atomicAdd(&fillV[v],1)] = i;
}

// ---------------- edge kernel: softmax + v2e aggregate + elu + [msg,S]@Wt+bt ----------------
__global__ __launch_bounds__(128) void k_edge(
    const int* __restrict__ V, const int* __restrict__ cntE,
    const int* __restrict__ startsE, const int* __restrict__ idxE,
    const float* __restrict__ scores, const float* __restrict__ Xfeat,
    const float* __restrict__ S, const float* __restrict__ Wt,
    const float* __restrict__ bt, float* __restrict__ Y) {
  __shared__ int   wvs[8][MAXC];
  __shared__ float wws[8][MAXC];
  __shared__ float msgT[192][8];
  __shared__ float ms[8], dens[8];
  __shared__ int   degs[8], sts[8];
  const int tid = threadIdx.x;
  const int lane = tid & 63, w = tid >> 6;
  const int e0 = blockIdx.x * 8;

  // phase A: per-edge softmax scalars (wave w owns edges w*4 .. w*4+3)
  for (int q = 0; q < 4; ++q) {
    const int t = w*4 + q;
    const int e = e0 + t;
    const int deg = cntE[e], st = startsE[e];
    float m = -INFINITY;
    for (int j = lane; j < deg; j += 64) {
      const int v = V[idxE[st + j]];
      m = fmaxf(m, leaky(scores[v]));
    }
    #pragma unroll
    for (int o = 32; o; o >>= 1) m = fmaxf(m, __shfl_xor(m, o, 64));
    float dsum = 0.f;
    for (int j = lane; j < deg; j += 64) {
      const int v = V[idxE[st + j]];
      const float ex = __expf(leaky(scores[v]) - m);
      dsum += ex;
      if (j < MAXC) { wvs[t][j] = v; wws[t][j] = ex; }
    }
    #pragma unroll
    for (int o = 32; o; o >>= 1) dsum += __shfl_xor(dsum, o, 64);
    if (lane == 0) { ms[t] = m; dens[t] = dsum; degs[t] = deg; sts[t] = st; }
  }
  __syncthreads();

  // S features into msgT[128..191][t]
  for (int p = tid; p < 8*STAR_; p += 128) {
    const int t = p >> 6, k = p & 63;
    msgT[128 + k][t] = S[(size_t)(e0 + t)*STAR_ + k];
  }

  // phase B: Y_v2e[e][c] = sum_j (ex_j/den) * Xfeat[v_j][c], then elu
  const int c = tid;
  for (int t = 0; t < 8; ++t) {
    const int deg = degs[t];
    float acc = 0.f;
    const int dc = deg < MAXC ? deg : MAXC;
    for (int j = 0; j < dc; ++j)
      acc += wws[t][j] * Xfeat[(size_t)wvs[t][j]*OUTC + c];
    for (int j = MAXC; j < deg; ++j) {            // statistically never taken
      const int v = V[idxE[sts[t] + j]];
      acc += __expf(leaky(scores[v]) - ms[t]) * Xfeat[(size_t)v*OUTC + c];
    }
    const float invd = deg > 0 ? 1.f/dens[t] : 0.f;
    msgT[c][t] = elu1(acc * invd);
  }
  __syncthreads();

  // phase C: Y[e] = msg(192) @ Wt(192x128) + bt
  float acc[8];
  const float btc = bt[c];
  #pragma unroll
  for (int t = 0; t < 8; ++t) acc[t] = btc;
  for (int k = 0; k < 192; ++k) {
    const float wt = Wt[k*OUTC + c];
    const float4 a0 = *(const float4*)&msgT[k][0];
    const float4 a1 = *(const float4*)&msgT[k][4];
    acc[0] += wt*a0.x; acc[1] += wt*a0.y; acc[2] += wt*a0.z; acc[3] += wt*a0.w;
    acc[4] += wt*a1.x; acc[5] += wt*a1.y; acc[6] += wt*a1.z; acc[7] += wt*a1.w;
  }
  #pragma unroll
  for (int t = 0; t < 8; ++t)
    Y[(size_t)(e0 + t)*OUTC + c] = acc[t];
}

// ---------------- node kernel: scatter-mean(Y[E]) by V, elu, + X_init ----------------
__global__ __launch_bounds__(128) void k_node(
    const int* __restrict__ E, const int* __restrict__ cntV,
    const int* __restrict__ startsV, const int* __restrict__ idxV,
    const float* __restrict__ Y, float* __restrict__ out /* holds X_init */) {
  __shared__ int elds[8][MAXC];
  __shared__ int degs[8], sts[8];
  const int tid = threadIdx.x;
  const int lane = tid & 63, w = tid >> 6;
  const int v0 = blockIdx.x * 8;
  for (int q = 0; q < 4; ++q) {
    const int t = w*4 + q;
    const int v = v0 + t;
    const int deg = cntV[v], st = startsV[v];
    for (int j = lane; j < deg && j < MAXC; j += 64)
      elds[t][j] = E[idxV[st + j]];
    if (lane == 0) { degs[t] = deg; sts[t] = st; }
  }
  __syncthreads();
  const int c = tid;
  for (int t = 0; t < 8; ++t) {
    const int deg = degs[t];
    float acc = 0.f;
    const int dc = deg < MAXC ? deg : MAXC;
    for (int j = 0; j < dc; ++j)
      acc += Y[(size_t)elds[t][j]*OUTC + c];
    for (int j = MAXC; j < deg; ++j)              // statistically never taken
      acc += Y[(size_t)E[idxV[sts[t]+j]]*OUTC + c];
    const float xn = acc / fmaxf((float)deg, 1.f);
    const size_t o = (size_t)(v0 + t)*OUTC + c;
    out[o] = elu1(xn) + out[o];
  }
}

extern "C" void kernel_launch(void* const* d_in, const int* in_sizes, int n_in,
                              void* d_out, int out_size, void* d_ws, size_t ws_size,
                              hipStream_t stream) {
  const float* X  = (const float*)d_in[0];
  const int*   V  = (const int*)d_in[1];
  const int*   E  = (const int*)d_in[2];
  const float* S  = (const float*)d_in[3];
  const float* Wx = (const float*)d_in[4];
  const float* bx = (const float*)d_in[5];
  const float* Wv = (const float*)d_in[6];
  const float* bv = (const float*)d_in[7];
  const float* av = (const float*)d_in[8];
  const float* Wt = (const float*)d_in[9];
  const float* bt = (const float*)d_in[10];
  float* out = (float*)d_out;

  char* ws = (char*)d_ws;
  size_t off = 0;
  auto alloc = [&](size_t bytes) -> void* {
    off = (off + 255) & ~(size_t)255;
    void* p = ws + off; off += bytes; return p;
  };
  float* Xfeat  = (float*)alloc((size_t)N_NODES*OUTC*4);
  float* scores = (float*)alloc((size_t)N_NODES*4);
  float* Y      = (float*)alloc((size_t)N_EDGES*OUTC*4);
  int* counters = (int*)alloc((size_t)600000*4); // cntE,fillE,cntV,fillV contiguous
  int* cntE  = counters;
  int* fillE = counters + 200000;
  int* cntV  = counters + 400000;
  int* fillV = counters + 500000;
  int* startsE = (int*)alloc((size_t)N_EDGES*4);
  int* startsV = (int*)alloc((size_t)N_NODES*4);
  int* idxE = (int*)alloc((size_t)NNZ_*4);
  int* idxV = (int*)alloc((size_t)NNZ_*4);
  int* partE = (int*)alloc(1024*4);
  int* partV = (int*)alloc(1024*4);

  hipMemsetAsync(counters, 0, (size_t)600000*4, stream);

  k_gemm1<<<N_NODES/8, 128, 0, stream>>>(X, Wx, bx, Wv, bv, out, Xfeat);
  k_scores<<<N_NODES/4, 256, 0, stream>>>(Xfeat, av, scores);
  k_hist<<<NNZ_/256, 256, 0, stream>>>(V, E, cntE, cntV);

  const int nbE = (N_EDGES + 255)/256;   // 782
  const int nbV = (N_NODES + 255)/256;   // 391
  k_scan_block<<<nbE, 256, 0, stream>>>(cntE, startsE, partE, N_EDGES);
  k_scan_partials<<<1, 1024, 0, stream>>>(partE, nbE);
  k_add_off<<<nbE, 256, 0, stream>>>(startsE, partE, N_EDGES);
  k_scan_block<<<nbV, 256, 0, stream>>>(cntV, startsV, partV, N_NODES);
  k_scan_partials<<<1, 1024, 0, stream>>>(partV, nbV);
  k_add_off<<<nbV, 256, 0, stream>>>(startsV, partV, N_NODES);

  k_fill<<<NNZ_/256, 256, 0, stream>>>(V, E, startsE, fillE, idxE, startsV, fillV, idxV);
  k_edge<<<N_EDGES/8, 128, 0, stream>>>(V, cntE, startsE, idxE, scores, Xfeat, S, Wt, bt, Y);
  k_node<<<N_NODES/8, 128, 0, stream>>>(E, cntV, startsV, idxV, Y, out);
}

// Round 2
// 1110.016 us; speedup vs baseline: 1.0291x; 1.0291x over previous
//
#include <hip/hip_runtime.h>
#include <math.h>

#define N_NODES 100000
#define N_EDGES 200000
#define NNZ_    1600000
#define INC  128
#define OUTC 128
#define STAR_ 64
#define NEG 0.2f
#define MAXE 32   // per-edge cached incidences (deg ~ Poisson(8), max ~30; tail loop correct anyway)
#define MAXN 64   // per-node cached incidences (deg ~ Poisson(16), max ~45)
#define MSTR 196  // msg row stride (floats): mult of 4 (16B-aligned float4), conflict-free writes

__device__ __forceinline__ float leaky(float x){ return x > 0.f ? x : NEG*x; }
__device__ __forceinline__ float elu1(float x){ return x > 0.f ? x : __expf(x)-1.f; }

// ---- GEMM1: X_init = X@Wx+bx (into d_out), X_feat = X@Wv+bv, scores = X_feat@a ----
__global__ __launch_bounds__(128) void k_gemm1(const float* __restrict__ X,
    const float* __restrict__ Wx, const float* __restrict__ bx,
    const float* __restrict__ Wv, const float* __restrict__ bv,
    const float* __restrict__ a,
    float* __restrict__ Xinit, float* __restrict__ Xfeat,
    float* __restrict__ scores) {
  __shared__ float xS[16][132];
  __shared__ float sred[16][2];
  const int c = threadIdx.x;
  const int lane = c & 63, w = c >> 6;
  const int r0 = blockIdx.x * 16;
  #pragma unroll
  for (int t = 0; t < 16; ++t) xS[t][c] = X[(size_t)(r0+t)*INC + c];
  __syncthreads();
  float ai[16], af[16];
  const float bxc = bx[c], bvc = bv[c], ac = a[c];
  #pragma unroll
  for (int t = 0; t < 16; ++t) { ai[t] = bxc; af[t] = bvc; }
  for (int k = 0; k < INC; k += 4) {
    const float wx0 = Wx[(k+0)*OUTC + c], wx1 = Wx[(k+1)*OUTC + c],
                wx2 = Wx[(k+2)*OUTC + c], wx3 = Wx[(k+3)*OUTC + c];
    const float wv0 = Wv[(k+0)*OUTC + c], wv1 = Wv[(k+1)*OUTC + c],
                wv2 = Wv[(k+2)*OUTC + c], wv3 = Wv[(k+3)*OUTC + c];
    #pragma unroll
    for (int t = 0; t < 16; ++t) {
      const float4 x4 = *(const float4*)&xS[t][k];
      ai[t] += x4.x*wx0 + x4.y*wx1 + x4.z*wx2 + x4.w*wx3;
      af[t] += x4.x*wv0 + x4.y*wv1 + x4.z*wv2 + x4.w*wv3;
    }
  }
  #pragma unroll
  for (int t = 0; t < 16; ++t) {
    Xinit[(size_t)(r0+t)*OUTC + c] = ai[t];
    Xfeat[(size_t)(r0+t)*OUTC + c] = af[t];
    float p = af[t] * ac;
    #pragma unroll
    for (int o = 32; o; o >>= 1) p += __shfl_xor(p, o, 64);
    if (lane == 0) sred[t][w] = p;
  }
  __syncthreads();
  if (c < 16) scores[r0 + c] = sred[c][0] + sred[c][1];
}

// ---------------- CSR build ----------------
__global__ void k_hist(const int* __restrict__ V, const int* __restrict__ E,
                       int* cntE, int* cntV) {
  const int i = blockIdx.x*256 + threadIdx.x;
  atomicAdd(&cntE[E[i]], 1);
  atomicAdd(&cntV[V[i]], 1);
}

__global__ void k_scan_block(const int* __restrict__ in, int* __restrict__ out,
                             int* __restrict__ partials, int n) {
  __shared__ int s[256];
  const int tid = threadIdx.x;
  const int i = blockIdx.x*256 + tid;
  const int v = (i < n) ? in[i] : 0;
  s[tid] = v; __syncthreads();
  for (int o = 1; o < 256; o <<= 1) {
    const int u = (tid >= o) ? s[tid-o] : 0;
    __syncthreads();
    s[tid] += u;
    __syncthreads();
  }
  if (i < n) out[i] = s[tid] - v;
  if (tid == 255) partials[blockIdx.x] = s[255];
}

__global__ void k_scan_partials(int* partials, int nb) {
  __shared__ int s[1024];
  const int tid = threadIdx.x;
  const int v = (tid < nb) ? partials[tid] : 0;
  s[tid] = v; __syncthreads();
  for (int o = 1; o < 1024; o <<= 1) {
    const int u = (tid >= o) ? s[tid-o] : 0;
    __syncthreads();
    s[tid] += u;
    __syncthreads();
  }
  if (tid < nb) partials[tid] = s[tid] - v;
}

__global__ void k_add_off(int* __restrict__ out, const int* __restrict__ partials, int n) {
  const int i = blockIdx.x*256 + threadIdx.x;
  if (i < n) out[i] += partials[blockIdx.x];
}

__global__ void k_fill(const int* __restrict__ V, const int* __restrict__ E,
    const int* __restrict__ startsE, int* fillE, int* __restrict__ idxE,
    const int* __restrict__ startsV, int* fillV, int* __restrict__ idxV) {
  const int i = blockIdx.x*256 + threadIdx.x;
  const int e = E[i]; idxE[startsE[e] + atomicAdd(&fillE[e],1)] = i;
  const int v = V[i]; idxV[startsV[v] + atomicAdd(&fillV[v],1)] = i;
}

// ---- edge kernel: softmax + v2e aggregate + elu + [msg,S]@Wt+bt ----
__global__ __launch_bounds__(128) void k_edge(
    const int* __restrict__ V, const int* __restrict__ cntE,
    const int* __restrict__ startsE, const int* __restrict__ idxE,
    const float* __restrict__ scores, const float* __restrict__ Xfeat,
    const float* __restrict__ S, const float* __restrict__ Wt,
    const float* __restrict__ bt, float* __restrict__ Y) {
  __shared__ int   wvs[8][MAXE];
  __shared__ float wws[8][MAXE];
  __shared__ float msg[8][MSTR];   // [t][0..127]=elu(Y_v2e), [t][128..191]=S
  __shared__ float ms[8], dens[8];
  __shared__ int   degs[8], sts[8];
  const int tid = threadIdx.x;
  const int lane = tid & 63, w = tid >> 6;
  const int e0 = blockIdx.x * 8;

  // zero-pad weight/index cache so phase B can run a padded unrolled loop
  #pragma unroll
  for (int p = tid; p < 8*MAXE; p += 128) {
    ((int*)wvs)[p] = 0;
    ((float*)wws)[p] = 0.f;
  }
  __syncthreads();

  // phase A: per-edge softmax scalars (wave w owns edges w*4 .. w*4+3)
  for (int q = 0; q < 4; ++q) {
    const int t = w*4 + q;
    const int e = e0 + t;
    const int deg = cntE[e], st = startsE[e];
    float m = -INFINITY;
    for (int j = lane; j < deg; j += 64) {
      const int v = V[idxE[st + j]];
      m = fmaxf(m, leaky(scores[v]));
    }
    #pragma unroll
    for (int o = 32; o; o >>= 1) m = fmaxf(m, __shfl_xor(m, o, 64));
    float dsum = 0.f;
    for (int j = lane; j < deg; j += 64) {
      const int v = V[idxE[st + j]];
      const float ex = __expf(leaky(scores[v]) - m);
      dsum += ex;
      if (j < MAXE) { wvs[t][j] = v; wws[t][j] = ex; }
    }
    #pragma unroll
    for (int o = 32; o; o >>= 1) dsum += __shfl_xor(dsum, o, 64);
    if (lane == 0) { ms[t] = m; dens[t] = dsum; degs[t] = deg; sts[t] = st; }
  }

  // S features into msg[t][128..191]
  for (int p = tid; p < 8*STAR_; p += 128) {
    const int t = p >> 6, k = p & 63;
    msg[t][128 + k] = S[(size_t)(e0 + t)*STAR_ + k];
  }
  __syncthreads();

  // phase B: Y_v2e[e][c] = sum_j (ex_j/den) * Xfeat[v_j][c], then elu
  const int c = tid;
  for (int t = 0; t < 8; ++t) {
    const int deg = degs[t];
    const int dc = deg < MAXE ? deg : MAXE;
    const int dc4 = (dc + 3) & ~3;
    float acc = 0.f;
    for (int j = 0; j < dc4; j += 4) {   // pad entries have weight 0, index 0 (safe)
      const int v0 = wvs[t][j+0], v1 = wvs[t][j+1], v2 = wvs[t][j+2], v3 = wvs[t][j+3];
      const float w0 = wws[t][j+0], w1 = wws[t][j+1], w2 = wws[t][j+2], w3 = wws[t][j+3];
      const float x0 = Xfeat[(size_t)v0*OUTC + c];
      const float x1 = Xfeat[(size_t)v1*OUTC + c];
      const float x2 = Xfeat[(size_t)v2*OUTC + c];
      const float x3 = Xfeat[(size_t)v3*OUTC + c];
      acc += w0*x0 + w1*x1 + w2*x2 + w3*x3;
    }
    for (int j = MAXE; j < deg; ++j) {            // statistically never taken
      const int v = V[idxE[sts[t] + j]];
      acc += __expf(leaky(scores[v]) - ms[t]) * Xfeat[(size_t)v*OUTC + c];
    }
    const float invd = deg > 0 ? 1.f/dens[t] : 0.f;
    msg[t][c] = elu1(acc * invd);
  }
  __syncthreads();

  // phase C: Y[e] = msg(192) @ Wt(192x128) + bt  (msg reads are same-addr broadcasts)
  float acc[8];
  const float btc = bt[c];
  #pragma unroll
  for (int t = 0; t < 8; ++t) acc[t] = btc;
  for (int k = 0; k < 192; k += 4) {
    const float wt0 = Wt[(k+0)*OUTC + c], wt1 = Wt[(k+1)*OUTC + c],
                wt2 = Wt[(k+2)*OUTC + c], wt3 = Wt[(k+3)*OUTC + c];
    #pragma unroll
    for (int t = 0; t < 8; ++t) {
      const float4 m4 = *(const float4*)&msg[t][k];
      acc[t] += wt0*m4.x + wt1*m4.y + wt2*m4.z + wt3*m4.w;
    }
  }
  #pragma unroll
  for (int t = 0; t < 8; ++t)
    Y[(size_t)(e0 + t)*OUTC + c] = acc[t];
}

// ---- node kernel: scatter-mean(Y[E]) by V, elu, + X_init ----
__global__ __launch_bounds__(128) void k_node(
    const int* __restrict__ E, const int* __restrict__ cntV,
    const int* __restrict__ startsV, const int* __restrict__ idxV,
    const float* __restrict__ Y, float* __restrict__ out /* holds X_init */) {
  __shared__ int elds[8][MAXN];
  __shared__ int degs[8], sts[8];
  const int tid = threadIdx.x;
  const int lane = tid & 63, w = tid >> 6;
  const int v0 = blockIdx.x * 8;
  #pragma unroll
  for (int p = tid; p < 8*MAXN; p += 128) ((int*)elds)[p] = 0;   // pad = valid row 0
  __syncthreads();
  for (int q = 0; q < 4; ++q) {
    const int t = w*4 + q;
    const int v = v0 + t;
    const int deg = cntV[v], st = startsV[v];
    for (int j = lane; j < deg && j < MAXN; j += 64)
      elds[t][j] = E[idxV[st + j]];
    if (lane == 0) { degs[t] = deg; sts[t] = st; }
  }
  __syncthreads();
  const int c = tid;
  for (int t = 0; t < 8; ++t) {
    const int deg = degs[t];
    const int dc = deg < MAXN ? deg : MAXN;
    const int dc4 = (dc + 3) & ~3;
    float acc = 0.f;
    for (int j = 0; j < dc4; j += 4) {
      const int e0 = elds[t][j+0], e1 = elds[t][j+1], e2 = elds[t][j+2], e3 = elds[t][j+3];
      const float p0 = (j+0 < dc) ? 1.f : 0.f;
      const float p1 = (j+1 < dc) ? 1.f : 0.f;
      const float p2 = (j+2 < dc) ? 1.f : 0.f;
      const float p3 = (j+3 < dc) ? 1.f : 0.f;
      acc += p0 * Y[(size_t)e0*OUTC + c] + p1 * Y[(size_t)e1*OUTC + c]
           + p2 * Y[(size_t)e2*OUTC + c] + p3 * Y[(size_t)e3*OUTC + c];
    }
    for (int j = MAXN; j < deg; ++j)              // statistically never taken
      acc += Y[(size_t)E[idxV[sts[t]+j]]*OUTC + c];
    const float xn = acc / fmaxf((float)deg, 1.f);
    const size_t o = (size_t)(v0 + t)*OUTC + c;
    out[o] = elu1(xn) + out[o];
  }
}

extern "C" void kernel_launch(void* const* d_in, const int* in_sizes, int n_in,
                              void* d_out, int out_size, void* d_ws, size_t ws_size,
                              hipStream_t stream) {
  const float* X  = (const float*)d_in[0];
  const int*   V  = (const int*)d_in[1];
  const int*   E  = (const int*)d_in[2];
  const float* S  = (const float*)d_in[3];
  const float* Wx = (const float*)d_in[4];
  const float* bx = (const float*)d_in[5];
  const float* Wv = (const float*)d_in[6];
  const float* bv = (const float*)d_in[7];
  const float* av = (const float*)d_in[8];
  const float* Wt = (const float*)d_in[9];
  const float* bt = (const float*)d_in[10];
  float* out = (float*)d_out;

  char* ws = (char*)d_ws;
  size_t off = 0;
  auto alloc = [&](size_t bytes) -> void* {
    off = (off + 255) & ~(size_t)255;
    void* p = ws + off; off += bytes; return p;
  };
  float* Xfeat  = (float*)alloc((size_t)N_NODES*OUTC*4);
  float* scores = (float*)alloc((size_t)N_NODES*4);
  float* Y      = (float*)alloc((size_t)N_EDGES*OUTC*4);
  int* counters = (int*)alloc((size_t)600000*4); // cntE,fillE,cntV,fillV contiguous
  int* cntE  = counters;
  int* fillE = counters + 200000;
  int* cntV  = counters + 400000;
  int* fillV = counters + 500000;
  int* startsE = (int*)alloc((size_t)N_EDGES*4);
  int* startsV = (int*)alloc((size_t)N_NODES*4);
  int* idxE = (int*)alloc((size_t)NNZ_*4);
  int* idxV = (int*)alloc((size_t)NNZ_*4);
  int* partE = (int*)alloc(1024*4);
  int* partV = (int*)alloc(1024*4);

  hipMemsetAsync(counters, 0, (size_t)600000*4, stream);

  k_gemm1<<<N_NODES/16, 128, 0, stream>>>(X, Wx, bx, Wv, bv, av, out, Xfeat, scores);
  k_hist<<<NNZ_/256, 256, 0, stream>>>(V, E, cntE, cntV);

  const int nbE = (N_EDGES + 255)/256;   // 782
  const int nbV = (N_NODES + 255)/256;   // 391
  k_scan_block<<<nbE, 256, 0, stream>>>(cntE, startsE, partE, N_EDGES);
  k_scan_partials<<<1, 1024, 0, stream>>>(partE, nbE);
  k_add_off<<<nbE, 256, 0, stream>>>(startsE, partE, N_EDGES);
  k_scan_block<<<nbV, 256, 0, stream>>>(cntV, startsV, partV, N_NODES);
  k_scan_partials<<<1, 1024, 0, stream>>>(partV, nbV);
  k_add_off<<<nbV, 256, 0, stream>>>(startsV, partV, N_NODES);

  k_fill<<<NNZ_/256, 256, 0, stream>>>(V, E, startsE, fillE, idxE, startsV, fillV, idxV);
  k_edge<<<N_EDGES/8, 128, 0, stream>>>(V, cntE, startsE, idxE, scores, Xfeat, S, Wt, bt, Y);
  k_node<<<N_NODES/8, 128, 0, stream>>>(E, cntV, startsV, idxV, Y, out);
}

// Round 3
// 775.635 us; speedup vs baseline: 1.4727x; 1.4311x over previous
//
#include <hip/hip_runtime.h>
#include <math.h>

#define N_NODES 100000
#define N_EDGES 200000
#define NNZ_    1600000
#define INC  128
#define OUTC 128
#define STAR_ 64
#define NEG 0.2f
#define MAXE 32   // per-edge cached incidences (deg ~ Poisson(8))
#define MAXN 64   // per-node cached incidences (deg ~ Poisson(16))

typedef __attribute__((ext_vector_type(8))) short bf16x8_t;
typedef __attribute__((ext_vector_type(4))) float f32x4_t;

__device__ __forceinline__ float leaky(float x){ return x > 0.f ? x : NEG*x; }
__device__ __forceinline__ float elu1(float x){ return x > 0.f ? x : __expf(x)-1.f; }
__device__ __forceinline__ unsigned short f2bf(float f){
  unsigned u = __float_as_uint(f);
  unsigned r = u + 0x7FFFu + ((u >> 16) & 1u);
  return (unsigned short)(r >> 16);
}
__device__ __forceinline__ float bf2f(unsigned short h){
  return __uint_as_float(((unsigned)h) << 16);
}

// ---- cvt: WcatT[256][128] = [Wx|Wv]^T bf16 ; WtT[128][192] = Wt^T bf16 ----
__global__ void k_cvt(const float* __restrict__ Wx, const float* __restrict__ Wv,
                      const float* __restrict__ Wt,
                      unsigned short* __restrict__ WcatT, unsigned short* __restrict__ WtT){
  const int i = blockIdx.x*256 + threadIdx.x;
  if (i < 256*128){
    const int n = i >> 7, k = i & 127;
    const float v = (n < 128) ? Wx[k*128 + n] : Wv[k*128 + (n-128)];
    WcatT[n*128 + k] = f2bf(v);
  }
  const int j = i - 256*128;
  if (j >= 0 && j < 128*192){
    const int n = j / 192, k = j - n*192;
    WtT[n*192 + k] = f2bf(Wt[k*128 + n]);
  }
}

// ---- GEMM1 (MFMA): [Xinit|Xfeat] = X @ [Wx|Wv] + [bx|bv]; Xinit fp32 -> d_out, Xfeat bf16 ----
__global__ __launch_bounds__(256) void k_gemm1(const float* __restrict__ X,
    const unsigned short* __restrict__ WcatT,
    const float* __restrict__ bx, const float* __restrict__ bv,
    float* __restrict__ Xinit, unsigned short* __restrict__ Xfb){
  __shared__ unsigned short xb[16][136];   // 128 bf16 + 8 pad (row=272B, 16B-aligned)
  const int tid = threadIdx.x;
  const int lane = tid & 63, w = tid >> 6;
  const int quad = lane >> 4, l16 = lane & 15;
  const int r0 = blockIdx.x * 16;
  {
    const int r = tid >> 4;             // 0..15
    const int c0 = (tid & 15) * 8;      // 0..120
    const float4 a4 = *(const float4*)&X[(size_t)(r0+r)*INC + c0];
    const float4 b4 = *(const float4*)&X[(size_t)(r0+r)*INC + c0 + 4];
    bf16x8_t pk;
    pk[0]=(short)f2bf(a4.x); pk[1]=(short)f2bf(a4.y); pk[2]=(short)f2bf(a4.z); pk[3]=(short)f2bf(a4.w);
    pk[4]=(short)f2bf(b4.x); pk[5]=(short)f2bf(b4.y); pk[6]=(short)f2bf(b4.z); pk[7]=(short)f2bf(b4.w);
    *(bf16x8_t*)&xb[r][c0] = pk;
  }
  __syncthreads();
  f32x4_t acc[4] = {{0,0,0,0},{0,0,0,0},{0,0,0,0},{0,0,0,0}};
  const int n_base = w*64 + l16;
  for (int s = 0; s < 4; ++s){
    const bf16x8_t af = *(const bf16x8_t*)&xb[l16][s*32 + quad*8];
    #pragma unroll
    for (int nt = 0; nt < 4; ++nt){
      const int n = n_base + nt*16;
      const bf16x8_t bf = *(const bf16x8_t*)&WcatT[(size_t)n*128 + s*32 + quad*8];
      acc[nt] = __builtin_amdgcn_mfma_f32_16x16x32_bf16(af, bf, acc[nt], 0, 0, 0);
    }
  }
  #pragma unroll
  for (int nt = 0; nt < 4; ++nt){
    const int n = n_base + nt*16;
    const float bias = (n < 128) ? bx[n] : bv[n-128];
    #pragma unroll
    for (int r = 0; r < 4; ++r){
      const int m = quad*4 + r;
      const float val = acc[nt][r] + bias;
      if (n < 128) Xinit[(size_t)(r0+m)*OUTC + n] = val;
      else         Xfb[(size_t)(r0+m)*OUTC + (n-128)] = f2bf(val);
    }
  }
}

// ---- scores = Xfeat @ a ----
__global__ __launch_bounds__(256) void k_scores(const unsigned short* __restrict__ Xfb,
    const float* __restrict__ a, float* __restrict__ scores){
  const int lane = threadIdx.x & 63;
  const int w = threadIdx.x >> 6;
  const int r = blockIdx.x * 4 + w;
  const unsigned pair = *(const unsigned*)&Xfb[(size_t)r*OUTC + lane*2];
  float p = bf2f((unsigned short)(pair & 0xffff)) * a[lane*2]
          + bf2f((unsigned short)(pair >> 16))    * a[lane*2+1];
  #pragma unroll
  for (int o = 32; o; o >>= 1) p += __shfl_xor(p, o, 64);
  if (lane == 0) scores[r] = p;
}

// ---------------- CSR build ----------------
__global__ void k_hist(const int* __restrict__ V, const int* __restrict__ E,
                       int* cntE, int* cntV) {
  const int i = blockIdx.x*256 + threadIdx.x;
  atomicAdd(&cntE[E[i]], 1);
  atomicAdd(&cntV[V[i]], 1);
}

__global__ void k_scan_block(const int* __restrict__ in, int* __restrict__ out,
                             int* __restrict__ partials, int n) {
  __shared__ int s[256];
  const int tid = threadIdx.x;
  const int i = blockIdx.x*256 + tid;
  const int v = (i < n) ? in[i] : 0;
  s[tid] = v; __syncthreads();
  for (int o = 1; o < 256; o <<= 1) {
    const int u = (tid >= o) ? s[tid-o] : 0;
    __syncthreads();
    s[tid] += u;
    __syncthreads();
  }
  if (i < n) out[i] = s[tid] - v;
  if (tid == 255) partials[blockIdx.x] = s[255];
}

__global__ void k_scan_partials(int* partials, int nb) {
  __shared__ int s[1024];
  const int tid = threadIdx.x;
  const int v = (tid < nb) ? partials[tid] : 0;
  s[tid] = v; __syncthreads();
  for (int o = 1; o < 1024; o <<= 1) {
    const int u = (tid >= o) ? s[tid-o] : 0;
    __syncthreads();
    s[tid] += u;
    __syncthreads();
  }
  if (tid < nb) partials[tid] = s[tid] - v;
}

__global__ void k_add_off(int* __restrict__ out, const int* __restrict__ partials, int n) {
  const int i = blockIdx.x*256 + threadIdx.x;
  if (i < n) out[i] += partials[blockIdx.x];
}

// stores gathered values directly: vIdxE[slot]=V[i], eIdxV[slot]=E[i]
__global__ void k_fill(const int* __restrict__ V, const int* __restrict__ E,
    const int* __restrict__ startsE, int* fillE, int* __restrict__ vIdxE,
    const int* __restrict__ startsV, int* fillV, int* __restrict__ eIdxV) {
  const int i = blockIdx.x*256 + threadIdx.x;
  const int e = E[i], v = V[i];
  vIdxE[startsE[e] + atomicAdd(&fillE[e],1)] = v;
  eIdxV[startsV[v] + atomicAdd(&fillV[v],1)] = e;
}

// ---- edge kernel: softmax + v2e aggregate + elu + MFMA [msg,S]@Wt + bt -> Y bf16 ----
__global__ __launch_bounds__(256) void k_edge(
    const int* __restrict__ cntE, const int* __restrict__ startsE,
    const int* __restrict__ vIdxE,
    const float* __restrict__ scores, const unsigned short* __restrict__ Xfb,
    const float* __restrict__ S, const unsigned short* __restrict__ WtT,
    const float* __restrict__ bt, unsigned short* __restrict__ Ybf) {
  __shared__ int   wvs[16][MAXE];
  __shared__ float wws[16][MAXE];
  __shared__ unsigned short msg[16][200];   // 192 bf16 + 8 pad (row=400B, 16B-aligned)
  __shared__ float ms[16], dens[16];
  __shared__ int   degs[16], sts[16];
  const int tid = threadIdx.x;
  const int lane = tid & 63, w = tid >> 6;
  const int e0 = blockIdx.x * 16;

  for (int p = tid; p < 16*MAXE; p += 256) { ((int*)wvs)[p] = 0; ((float*)wws)[p] = 0.f; }
  __syncthreads();

  // phase A: per-edge softmax scalars (wave w owns edges w*4 .. w*4+3)
  for (int q = 0; q < 4; ++q) {
    const int t = w*4 + q;
    const int e = e0 + t;
    const int deg = cntE[e], st = startsE[e];
    float m = -INFINITY;
    for (int j = lane; j < deg; j += 64)
      m = fmaxf(m, leaky(scores[vIdxE[st + j]]));
    #pragma unroll
    for (int o = 32; o; o >>= 1) m = fmaxf(m, __shfl_xor(m, o, 64));
    float dsum = 0.f;
    for (int j = lane; j < deg; j += 64) {
      const int v = vIdxE[st + j];
      const float ex = __expf(leaky(scores[v]) - m);
      dsum += ex;
      if (j < MAXE) { wvs[t][j] = v; wws[t][j] = ex; }
    }
    #pragma unroll
    for (int o = 32; o; o >>= 1) dsum += __shfl_xor(dsum, o, 64);
    if (lane == 0) { ms[t] = m; dens[t] = dsum; degs[t] = deg; sts[t] = st; }
  }
  __syncthreads();

  // phase B: thread handles 2 edges x 4 channels
  const int sub = tid & 31, grp = tid >> 5;   // grp 0..7
  const int c4 = sub * 4;
  // S features -> msg[t][128..191] (bf16)
  if (sub < 16) {
    const int cs = sub * 4;
    #pragma unroll
    for (int tt = 0; tt < 2; ++tt) {
      const int t = grp*2 + tt;
      const float4 s4 = *(const float4*)&S[(size_t)(e0+t)*STAR_ + cs];
      ushort4 pk; pk.x=f2bf(s4.x); pk.y=f2bf(s4.y); pk.z=f2bf(s4.z); pk.w=f2bf(s4.w);
      *(ushort4*)&msg[t][128 + cs] = pk;
    }
  }
  #pragma unroll
  for (int tt = 0; tt < 2; ++tt) {
    const int t = grp*2 + tt;
    const int deg = degs[t];
    const int dc = deg < MAXE ? deg : MAXE;
    const int dc4 = (dc + 3) & ~3;
    float a0=0.f, a1=0.f, a2=0.f, a3=0.f;
    for (int j = 0; j < dc4; j += 4) {     // pad entries: weight 0, index 0 (safe)
      #pragma unroll
      for (int ii = 0; ii < 4; ++ii) {
        const int v = wvs[t][j+ii];
        const float wgt = wws[t][j+ii];
        const ushort4 x = *(const ushort4*)&Xfb[(size_t)v*OUTC + c4];
        a0 += wgt * bf2f(x.x); a1 += wgt * bf2f(x.y);
        a2 += wgt * bf2f(x.z); a3 += wgt * bf2f(x.w);
      }
    }
    for (int j = MAXE; j < deg; ++j) {     // statistically never taken
      const int v = vIdxE[sts[t] + j];
      const float wgt = __expf(leaky(scores[v]) - ms[t]);
      const ushort4 x = *(const ushort4*)&Xfb[(size_t)v*OUTC + c4];
      a0 += wgt * bf2f(x.x); a1 += wgt * bf2f(x.y);
      a2 += wgt * bf2f(x.z); a3 += wgt * bf2f(x.w);
    }
    const float invd = deg > 0 ? 1.f/dens[t] : 0.f;
    ushort4 pk;
    pk.x = f2bf(elu1(a0*invd)); pk.y = f2bf(elu1(a1*invd));
    pk.z = f2bf(elu1(a2*invd)); pk.w = f2bf(elu1(a3*invd));
    *(ushort4*)&msg[t][c4] = pk;
  }
  __syncthreads();

  // phase C: Y[16 edges][128] = msg(16x192) @ Wt(192x128) + bt via MFMA
  const int quad = lane >> 4, l16 = lane & 15;
  f32x4_t acc0 = {0,0,0,0}, acc1 = {0,0,0,0};
  const int n0 = w * 32;
  for (int s = 0; s < 6; ++s) {
    const bf16x8_t af = *(const bf16x8_t*)&msg[l16][s*32 + quad*8];
    const bf16x8_t b0 = *(const bf16x8_t*)&WtT[(size_t)(n0 + l16)*192      + s*32 + quad*8];
    const bf16x8_t b1 = *(const bf16x8_t*)&WtT[(size_t)(n0 + 16 + l16)*192 + s*32 + quad*8];
    acc0 = __builtin_amdgcn_mfma_f32_16x16x32_bf16(af, b0, acc0, 0, 0, 0);
    acc1 = __builtin_amdgcn_mfma_f32_16x16x32_bf16(af, b1, acc1, 0, 0, 0);
  }
  const float bt0 = bt[n0 + l16], bt1 = bt[n0 + 16 + l16];
  #pragma unroll
  for (int r = 0; r < 4; ++r) {
    const int m = quad*4 + r;
    Ybf[(size_t)(e0+m)*OUTC + n0 + l16]      = f2bf(acc0[r] + bt0);
    Ybf[(size_t)(e0+m)*OUTC + n0 + 16 + l16] = f2bf(acc1[r] + bt1);
  }
}

// ---- node kernel: scatter-mean(Y[E]) by V, elu, + X_init ----
__global__ __launch_bounds__(128) void k_node(
    const int* __restrict__ cntV, const int* __restrict__ startsV,
    const int* __restrict__ eIdxV,
    const unsigned short* __restrict__ Ybf, float* __restrict__ out) {
  __shared__ int elds[8][MAXN];
  __shared__ int degs[8], sts[8];
  const int tid = threadIdx.x;
  const int lane = tid & 63, w = tid >> 6;
  const int v0 = blockIdx.x * 8;
  #pragma unroll
  for (int p = tid; p < 8*MAXN; p += 128) ((int*)elds)[p] = 0;
  __syncthreads();
  for (int q = 0; q < 4; ++q) {
    const int t = w*4 + q;
    const int v = v0 + t;
    const int deg = cntV[v], st = startsV[v];
    for (int j = lane; j < deg && j < MAXN; j += 64)
      elds[t][j] = eIdxV[st + j];
    if (lane == 0) { degs[t] = deg; sts[t] = st; }
  }
  __syncthreads();
  const int sub = tid & 31, grp = tid >> 5;   // grp 0..3
  const int c4 = sub * 4;
  #pragma unroll
  for (int tt = 0; tt < 2; ++tt) {
    const int t = grp*2 + tt;
    const int deg = degs[t];
    const int dc = deg < MAXN ? deg : MAXN;
    const int dc4 = (dc + 3) & ~3;
    float a0=0.f, a1=0.f, a2=0.f, a3=0.f;
    for (int j = 0; j < dc4; j += 4) {
      #pragma unroll
      for (int ii = 0; ii < 4; ++ii) {
        const int e = elds[t][j+ii];
        const float pz = (j+ii < dc) ? 1.f : 0.f;
        const ushort4 y = *(const ushort4*)&Ybf[(size_t)e*OUTC + c4];
        a0 += pz * bf2f(y.x); a1 += pz * bf2f(y.y);
        a2 += pz * bf2f(y.z); a3 += pz * bf2f(y.w);
      }
    }
    for (int j = MAXN; j < deg; ++j) {     // statistically never taken
      const int e = eIdxV[sts[t] + j];
      const ushort4 y = *(const ushort4*)&Ybf[(size_t)e*OUTC + c4];
      a0 += bf2f(y.x); a1 += bf2f(y.y); a2 += bf2f(y.z); a3 += bf2f(y.w);
    }
    const float invd = 1.f / fmaxf((float)deg, 1.f);
    float4 o = *(float4*)&out[(size_t)(v0+t)*OUTC + c4];
    o.x = elu1(a0*invd) + o.x;
    o.y = elu1(a1*invd) + o.y;
    o.z = elu1(a2*invd) + o.z;
    o.w = elu1(a3*invd) + o.w;
    *(float4*)&out[(size_t)(v0+t)*OUTC + c4] = o;
  }
}

extern "C" void kernel_launch(void* const* d_in, const int* in_sizes, int n_in,
                              void* d_out, int out_size, void* d_ws, size_t ws_size,
                              hipStream_t stream) {
  const float* X  = (const float*)d_in[0];
  const int*   V  = (const int*)d_in[1];
  const int*   E  = (const int*)d_in[2];
  const float* S  = (const float*)d_in[3];
  const float* Wx = (const float*)d_in[4];
  const float* bx = (const float*)d_in[5];
  const float* Wv = (const float*)d_in[6];
  const float* bv = (const float*)d_in[7];
  const float* av = (const float*)d_in[8];
  const float* Wt = (const float*)d_in[9];
  const float* bt = (const float*)d_in[10];
  float* out = (float*)d_out;

  char* ws = (char*)d_ws;
  size_t off = 0;
  auto alloc = [&](size_t bytes) -> void* {
    off = (off + 255) & ~(size_t)255;
    void* p = ws + off; off += bytes; return p;
  };
  unsigned short* Xfb   = (unsigned short*)alloc((size_t)N_NODES*OUTC*2);
  unsigned short* Ybf   = (unsigned short*)alloc((size_t)N_EDGES*OUTC*2);
  float* scores = (float*)alloc((size_t)N_NODES*4);
  unsigned short* WcatT = (unsigned short*)alloc((size_t)256*128*2);
  unsigned short* WtT   = (unsigned short*)alloc((size_t)128*192*2);
  int* counters = (int*)alloc((size_t)600000*4); // cntE,fillE,cntV,fillV contiguous
  int* cntE  = counters;
  int* fillE = counters + 200000;
  int* cntV  = counters + 400000;
  int* fillV = counters + 500000;
  int* startsE = (int*)alloc((size_t)N_EDGES*4);
  int* startsV = (int*)alloc((size_t)N_NODES*4);
  int* vIdxE = (int*)alloc((size_t)NNZ_*4);
  int* eIdxV = (int*)alloc((size_t)NNZ_*4);
  int* partE = (int*)alloc(1024*4);
  int* partV = (int*)alloc(1024*4);

  hipMemsetAsync(counters, 0, (size_t)600000*4, stream);

  k_cvt<<<(256*128 + 128*192 + 255)/256, 256, 0, stream>>>(Wx, Wv, Wt, WcatT, WtT);
  k_gemm1<<<N_NODES/16, 256, 0, stream>>>(X, WcatT, bx, bv, out, Xfb);
  k_scores<<<N_NODES/4, 256, 0, stream>>>(Xfb, av, scores);
  k_hist<<<NNZ_/256, 256, 0, stream>>>(V, E, cntE, cntV);

  const int nbE = (N_EDGES + 255)/256;   // 782
  const int nbV = (N_NODES + 255)/256;   // 391
  k_scan_block<<<nbE, 256, 0, stream>>>(cntE, startsE, partE, N_EDGES);
  k_scan_partials<<<1, 1024, 0, stream>>>(partE, nbE);
  k_add_off<<<nbE, 256, 0, stream>>>(startsE, partE, N_EDGES);
  k_scan_block<<<nbV, 256, 0, stream>>>(cntV, startsV, partV, N_NODES);
  k_scan_partials<<<1, 1024, 0, stream>>>(partV, nbV);
  k_add_off<<<nbV, 256, 0, stream>>>(startsV, partV, N_NODES);

  k_fill<<<NNZ_/256, 256, 0, stream>>>(V, E, startsE, fillE, vIdxE, startsV, fillV, eIdxV);
  k_edge<<<N_EDGES/16, 256, 0, stream>>>(cntE, startsE, vIdxE, scores, Xfb, S, WtT, bt, Ybf);
  k_node<<<N_NODES/8, 128, 0, stream>>>(cntV, startsV, eIdxV, Ybf, out);
}